// Round 6
// baseline (284.940 us; speedup 1.0000x reference)
//
#include <hip/hip_runtime.h>

constexpr int N_NODES = 100000;
constexpr int N_EDGES = 1600000;
constexpr int F = 128;
constexpr int H = 8;
constexpr float ALPHA = 0.2f;
constexpr float EPSF = 1e-12f;

constexpr int PSHIFT = 8;                         // 256 nodes per partition
constexpr int PN = 1 << PSHIFT;                   // 256
constexpr int NPART = (N_NODES + PN - 1) / PN;    // 391
constexpr int MAXPART = 5120;                     // mean 4096 + ~16 sigma
constexpr int EPB = 4096;                         // edges per block in pass A
constexpr int OCAP = 4096;                        // overflow list capacity
constexpr int UNR = 8;                            // kB MLP unroll

// K1: per-node scores; aa staged in LDS (broadcast reads, conflict-free).
// s_src -> srn[n*16 + 0..7] (rinv fills +8..15 later); s_dst separate.
__global__ void k1_scores(const float* __restrict__ x, const float* __restrict__ aa,
                          float* __restrict__ srn, float* __restrict__ s_dst) {
    __shared__ float sa[H * 2 * F];
    for (int i = threadIdx.x; i < H * 2 * F; i += blockDim.x) sa[i] = aa[i];
    __syncthreads();
    int node = blockIdx.x * blockDim.x + threadIdx.x;
    if (node >= N_NODES) return;
    const float4* xr = reinterpret_cast<const float4*>(x + (size_t)node * F);
    float accs[H], accd[H];
#pragma unroll
    for (int h = 0; h < H; ++h) { accs[h] = 0.f; accd[h] = 0.f; }
    for (int f4 = 0; f4 < F / 4; ++f4) {
        float4 xv = xr[f4];
#pragma unroll
        for (int h = 0; h < H; ++h) {
            float4 av = *reinterpret_cast<const float4*>(&sa[h * 2 * F + 4 * f4]);
            float4 bv = *reinterpret_cast<const float4*>(&sa[h * 2 * F + F + 4 * f4]);
            accs[h] += xv.x * av.x + xv.y * av.y + xv.z * av.z + xv.w * av.w;
            accd[h] += xv.x * bv.x + xv.y * bv.y + xv.z * bv.z + xv.w * bv.w;
        }
    }
    float4* os = reinterpret_cast<float4*>(srn + (size_t)node * 16);
    os[0] = make_float4(accs[0], accs[1], accs[2], accs[3]);
    os[1] = make_float4(accs[4], accs[5], accs[6], accs[7]);
    float4* od = reinterpret_cast<float4*>(s_dst + (size_t)node * H);
    od[0] = make_float4(accd[0], accd[1], accd[2], accd[3]);
    od[1] = make_float4(accd[4], accd[5], accd[6], accd[7]);
}

// Pass A: radix-partition edges by row>>8. One global atomic per (block,partition).
// Payload u32 = (row&255)<<17 | col  (col < 2^17).
__global__ void __launch_bounds__(1024)
kA_part(const int* __restrict__ row, const int* __restrict__ col,
        int* __restrict__ gcnt, unsigned* __restrict__ part,
        int* __restrict__ ocnt, int2* __restrict__ olist) {
    __shared__ int hist[NPART];
    __shared__ int base[NPART];
    const int t = threadIdx.x;
    const int e0 = blockIdx.x * EPB;
    for (int p = t; p < NPART; p += 1024) hist[p] = 0;
    __syncthreads();
    for (int k = 0; k < EPB / 1024; ++k) {
        int i = e0 + k * 1024 + t;
        if (i < N_EDGES) atomicAdd(&hist[row[i] >> PSHIFT], 1);
    }
    __syncthreads();
    for (int p = t; p < NPART; p += 1024) {
        int h = hist[p];
        base[p] = h ? atomicAdd(&gcnt[p], h) : 0;
        hist[p] = 0;  // reuse as cursor
    }
    __syncthreads();
    for (int k = 0; k < EPB / 1024; ++k) {
        int i = e0 + k * 1024 + t;
        if (i < N_EDGES) {
            int r = row[i], c = col[i];
            int p = r >> PSHIFT;
            int slot = base[p] + atomicAdd(&hist[p], 1);
            unsigned pk = ((unsigned)(r & (PN - 1)) << 17) | (unsigned)c;
            if (slot < MAXPART) {
                part[(size_t)p * MAXPART + slot] = pk;
            } else {
                int q = atomicAdd(ocnt, 1);
                if (q < OCAP) olist[q] = make_int2(p, (int)pk);
            }
        }
    }
}

// Pass B: one block (1024 thr) per partition; head-split (thread owns h=t&7,
// 8 lanes per edge). 8-way unrolled with BATCHED independent loads: 8 pk
// loads in flight, then 8 s_dst gathers in flight (MLP=8/wave, was 1).
__global__ void __launch_bounds__(1024)
kB_sum(const float* __restrict__ s_dst, const unsigned* __restrict__ part,
       const int* __restrict__ gcnt, const int* __restrict__ ocnt,
       const int2* __restrict__ olist, float* __restrict__ srn) {
    __shared__ float acc[PN * H];    // 8 KB
    __shared__ float ssrc[PN * H];   // 8 KB
    const int p = blockIdx.x;
    const int t = threadIdx.x;
    const int nbase = p << PSHIFT;
    for (int j = t; j < PN * H; j += 1024) {
        int n = nbase + (j >> 3);
        ssrc[j] = (n < N_NODES) ? srn[(size_t)n * 16 + (j & 7)] : 0.f;
        acc[j] = 0.f;
    }
    __syncthreads();
    int cnt = gcnt[p]; if (cnt > MAXPART) cnt = MAXPART;
    const unsigned* pp = part + (size_t)p * MAXPART;
    const int total = cnt * H;
    const int h = t & 7;             // stride 1024 preserves j&7 == t&7
    int j = t;
    for (; j + (UNR - 1) * 1024 < total; j += UNR * 1024) {
        unsigned pk[UNR];
        float bv[UNR];
#pragma unroll
        for (int u = 0; u < UNR; ++u) pk[u] = pp[(j + u * 1024) >> 3];
#pragma unroll
        for (int u = 0; u < UNR; ++u) bv[u] = s_dst[(size_t)(pk[u] & 0x1FFFFu) * H + h];
#pragma unroll
        for (int u = 0; u < UNR; ++u) {
            int rl = (int)(pk[u] >> 17);
            float e = ssrc[rl * H + h] + bv[u];
            e = e > 0.f ? e : ALPHA * e;
            atomicAdd(&acc[rl * H + h], __expf(e));
        }
    }
    for (; j < total; j += 1024) {
        unsigned pk = pp[j >> 3];
        int c = (int)(pk & 0x1FFFFu);
        int rl = (int)(pk >> 17);
        float e = ssrc[rl * H + h] + s_dst[(size_t)c * H + h];
        e = e > 0.f ? e : ALPHA * e;
        atomicAdd(&acc[rl * H + h], __expf(e));
    }
    // overflow edges (expected: none)
    int m = *ocnt; if (m > OCAP) m = OCAP;
    for (int jo = t; jo < m; jo += 1024) {
        int2 oe = olist[jo];
        if (oe.x == p) {
            unsigned pk = (unsigned)oe.y;
            int c = (int)(pk & 0x1FFFFu);
            int rl = (int)(pk >> 17);
#pragma unroll
            for (int hh = 0; hh < H; ++hh) {
                float e = ssrc[rl * H + hh] + s_dst[(size_t)c * H + hh];
                e = e > 0.f ? e : ALPHA * e;
                atomicAdd(&acc[rl * H + hh], __expf(e));
            }
        }
    }
    __syncthreads();
    for (int jw = t; jw < PN * H; jw += 1024) {
        int n = nbase + (jw >> 3);
        if (n < N_NODES) srn[(size_t)n * 16 + 8 + (jw & 7)] = 1.0f / (acc[jw] + EPSF);
    }
}

// K4: normalize; one 64B line per row-gather (s_src+rinv), 32B per col-gather.
__global__ void k4_out(const int* __restrict__ row, const int* __restrict__ col,
                       const float* __restrict__ srn, const float* __restrict__ s_dst,
                       float* __restrict__ out) {
    int i = blockIdx.x * blockDim.x + threadIdx.x;
    if (i >= N_EDGES) return;
    int r = row[i], c = col[i];
    const float4* sr = reinterpret_cast<const float4*>(srn + (size_t)r * 16);
    float4 a0 = sr[0], a1 = sr[1], r0 = sr[2], r1 = sr[3];
    const float4* sc = reinterpret_cast<const float4*>(s_dst + (size_t)c * H);
    float4 b0 = sc[0], b1 = sc[1];
    float ev[H] = {a0.x + b0.x, a0.y + b0.y, a0.z + b0.z, a0.w + b0.w,
                   a1.x + b1.x, a1.y + b1.y, a1.z + b1.z, a1.w + b1.w};
    float rv[H] = {r0.x, r0.y, r0.z, r0.w, r1.x, r1.y, r1.z, r1.w};
#pragma unroll
    for (int h = 0; h < H; ++h) {
        float e = ev[h] > 0.f ? ev[h] : ALPHA * ev[h];
        out[(size_t)h * N_EDGES + i] = __expf(e) * rv[h];
    }
}

// ---------------- atomic fallback (tiny ws) ----------------
__global__ void kz_zero_sums(float* __restrict__ srn) {
    int t = blockIdx.x * blockDim.x + threadIdx.x;
    if (t >= N_NODES * H) return;
    srn[(size_t)(t >> 3) * 16 + 8 + (t & 7)] = 0.f;
}

__global__ void k3nm_sum(const float* __restrict__ srn_ro, const float* __restrict__ s_dst,
                         const int* __restrict__ row, const int* __restrict__ col,
                         float* __restrict__ srn) {
    int i = blockIdx.x * blockDim.x + threadIdx.x;
    if (i >= N_EDGES) return;
    int r = row[i], c = col[i];
    const float4* sr = reinterpret_cast<const float4*>(srn_ro + (size_t)r * 16);
    float4 a0 = sr[0], a1 = sr[1];
    const float4* sc = reinterpret_cast<const float4*>(s_dst + (size_t)c * H);
    float4 b0 = sc[0], b1 = sc[1];
    float ev[H] = {a0.x + b0.x, a0.y + b0.y, a0.z + b0.z, a0.w + b0.w,
                   a1.x + b1.x, a1.y + b1.y, a1.z + b1.z, a1.w + b1.w};
#pragma unroll
    for (int h = 0; h < H; ++h) {
        float e = ev[h] > 0.f ? ev[h] : ALPHA * ev[h];
        atomicAdd(&srn[(size_t)r * 16 + 8 + h], __expf(e));
    }
}

__global__ void k_inv(float* __restrict__ srn) {
    int t = blockIdx.x * blockDim.x + threadIdx.x;
    if (t >= N_NODES * H) return;
    int n = t >> 3, h = t & 7;
    float s = srn[(size_t)n * 16 + 8 + h];
    srn[(size_t)n * 16 + 8 + h] = 1.0f / (s + EPSF);
}

extern "C" void kernel_launch(void* const* d_in, const int* in_sizes, int n_in,
                              void* d_out, int out_size, void* d_ws, size_t ws_size,
                              hipStream_t stream) {
    const float* x   = (const float*)d_in[0];
    const int*   row = (const int*)d_in[1];
    const int*   col = (const int*)d_in[2];
    const float* aa  = (const float*)d_in[3];
    float* out = (float*)d_out;

    // ws layout: srn (100k*16 f) | s_dst (100k*8 f) | part | gcnt | ocnt(16) | olist
    float*    srn   = (float*)d_ws;
    float*    s_dst = srn + (size_t)N_NODES * 16;
    unsigned* part  = (unsigned*)(s_dst + (size_t)N_NODES * H);
    int*      gcnt  = (int*)(part + (size_t)NPART * MAXPART);
    int*      ocnt  = gcnt + NPART;
    int2*     olist = (int2*)(ocnt + 16);

    const size_t need_b = ((size_t)N_NODES * 24 + (size_t)NPART * MAXPART
                           + NPART + 16 + 2 * OCAP) * 4;  // ~17.7 MB

    const int B = 256;
    const int GE = (N_EDGES + B - 1) / B;
    const int GN = (N_NODES + B - 1) / B;

    k1_scores<<<GN, B, 0, stream>>>(x, aa, srn, s_dst);

    if (ws_size >= need_b) {
        hipMemsetAsync(gcnt, 0, (size_t)(NPART + 16) * sizeof(int), stream);
        kA_part<<<(N_EDGES + EPB - 1) / EPB, 1024, 0, stream>>>(row, col, gcnt, part, ocnt, olist);
        kB_sum<<<NPART, 1024, 0, stream>>>(s_dst, part, gcnt, ocnt, olist, srn);
    } else {
        kz_zero_sums<<<(N_NODES * H + B - 1) / B, B, 0, stream>>>(srn);
        k3nm_sum<<<GE, B, 0, stream>>>(srn, s_dst, row, col, srn);
        k_inv<<<(N_NODES * H + B - 1) / B, B, 0, stream>>>(srn);
    }

    k4_out<<<GE, B, 0, stream>>>(row, col, srn, s_dst, out);
}